// Round 6
// baseline (287.500 us; speedup 1.0000x reference)
//
#include <hip/hip_runtime.h>
#include <hip/hip_bf16.h>

#define BATCH 64
#define CDIM  256
#define MHW   196
#define MP    224      // padded K for covariance (multiple of 32)
#define EDIM  512
#define CC    65536    // CDIM*CDIM
#define NTRI  10       // upper-triangle 64x64 tiles of a 256x256 matrix
#define WCONV_BLOCKS 2048   // 2048 * 16384 = 33,554,432 = CC*EDIM f32 elements

typedef __attribute__((ext_vector_type(8))) short short8_t;   // 8 x bf16 MFMA frag
typedef __attribute__((ext_vector_type(4))) float f32x4;

static __device__ __forceinline__ unsigned short f2bfu(float f) {
    __hip_bfloat16 h = __float2bfloat16(f);
    return __builtin_bit_cast(unsigned short, h);
}

// ---------------------------------------------------------------------------
// center_row: one wave centers one local row (0..255) of batch b,
// bf16-cast (pad to MP), per-row sum-of-squares -> rs[row] (LDS).
// ---------------------------------------------------------------------------
static __device__ __forceinline__ void center_row(
    const float* __restrict__ feat_b, __hip_bfloat16* __restrict__ xcb_b,
    float* __restrict__ rs, int row, int l)
{
    const float* src = feat_b + (size_t)row * MHW;
    float v0 = src[l];
    float v1 = src[l + 64];
    float v2 = src[l + 128];
    float v3 = (l + 192 < MHW) ? src[l + 192] : 0.0f;
    float s = v0 + v1 + v2 + v3;
    #pragma unroll
    for (int o = 32; o >= 1; o >>= 1) s += __shfl_xor(s, o, 64);
    const float mean = s * (1.0f / MHW);
    v0 -= mean; v1 -= mean; v2 -= mean;
    v3 = (l + 192 < MHW) ? (v3 - mean) : 0.0f;
    float sq = v0*v0 + v1*v1 + v2*v2 + v3*v3;
    #pragma unroll
    for (int o = 32; o >= 1; o >>= 1) sq += __shfl_xor(sq, o, 64);
    if (l == 0) rs[row] = sq;
    __hip_bfloat16* dst = xcb_b + (size_t)row * MP;
    dst[l]       = __float2bfloat16(v0);
    dst[l + 64]  = __float2bfloat16(v1);
    dst[l + 128] = __float2bfloat16(v2);
    if (l + 192 < MP) dst[l + 192] = __float2bfloat16(v3);   // zero pad to MP
}

// ---------------------------------------------------------------------------
// mm64: one wave computes one 64x64 upper-triangle tile t of
// out = a*(A@B) + beta*D + gamma*I  (per-batch pointers, stride KT for A/B,
// 256 for D/out). Both operands stored exactly symmetric (mirror writes), so
// row-reads of B give B^T columns. Direct global reads (L2-resident), f32
// accum, bf16 out. Returns Frobenius-norm^2 partial if NORM.
// ---------------------------------------------------------------------------
template<int KT, bool NORM>
static __device__ __forceinline__ float mm64(
    const __hip_bfloat16* __restrict__ A, const __hip_bfloat16* __restrict__ Bm,
    const __hip_bfloat16* __restrict__ D, __hip_bfloat16* __restrict__ out,
    float a, float beta, float gamma, int t, int l)
{
    int ti, tj;
    if (t < 4)      { ti = 0; tj = t; }
    else if (t < 7) { ti = 1; tj = t - 3; }
    else if (t < 9) { ti = 2; tj = t - 5; }
    else            { ti = 3; tj = 3; }
    const int lr = l & 15, lg = l >> 4;

    f32x4 acc[4][4];
    #pragma unroll
    for (int i = 0; i < 4; i++)
        #pragma unroll
        for (int j = 0; j < 4; j++)
            #pragma unroll
            for (int r = 0; r < 4; r++) acc[i][j][r] = 0.0f;

    const __hip_bfloat16* Ab = A  + (size_t)(ti * 64 + lr) * KT;
    const __hip_bfloat16* Bb = Bm + (size_t)(tj * 64 + lr) * KT;
    for (int k0 = 0; k0 < KT; k0 += 32) {        // same k order as prior rounds
        const int k = k0 + lg * 8;
        short8_t af[4], bfr[4];
        #pragma unroll
        for (int i = 0; i < 4; i++)
            af[i] = *reinterpret_cast<const short8_t*>(Ab + (size_t)i * 16 * KT + k);
        #pragma unroll
        for (int j = 0; j < 4; j++)
            bfr[j] = *reinterpret_cast<const short8_t*>(Bb + (size_t)j * 16 * KT + k);
        #pragma unroll
        for (int i = 0; i < 4; i++)
            #pragma unroll
            for (int j = 0; j < 4; j++)
                acc[i][j] = __builtin_amdgcn_mfma_f32_16x16x32_bf16(af[i], bfr[j], acc[i][j], 0, 0, 0);
    }

    float ns = 0.0f;
    #pragma unroll
    for (int i = 0; i < 4; i++) {
        #pragma unroll
        for (int j = 0; j < 4; j++) {
            #pragma unroll
            for (int r = 0; r < 4; r++) {
                const int grow = ti * 64 + i * 16 + lg * 4 + r;
                const int gcol = tj * 64 + j * 16 + lr;
                float v = a * acc[i][j][r];
                if (D) v += beta * __bfloat162float(D[grow * 256 + gcol]);
                if (grow == gcol) v += gamma;
                const __hip_bfloat16 hv = __float2bfloat16(v);
                out[grow * 256 + gcol] = hv;
                if (ti != tj) out[gcol * 256 + grow] = hv;   // exact-symmetry mirror
                if (NORM) {
                    const float fv = __bfloat162float(hv);
                    ns += ((ti != tj) ? 2.0f : 1.0f) * fv * fv;
                }
            }
        }
    }
    return ns;
}

// ---------------------------------------------------------------------------
// k_mega: blocks 0..63 = full per-batch NS chain on one CU (16 waves, only
// __syncthreads between steps — round-5 showed grid.sync costs ~more than a
// launch). Blocks 64.. = W f32->bf16 conversion, overlapped (independent).
// ---------------------------------------------------------------------------
__global__ __launch_bounds__(1024) void k_mega(
    const float* __restrict__ feat, const float* __restrict__ W,
    __hip_bfloat16* __restrict__ xcb_all, __hip_bfloat16* __restrict__ Wbf,
    __hip_bfloat16* __restrict__ M0, __hip_bfloat16* __restrict__ M1,
    __hip_bfloat16* __restrict__ M2, __hip_bfloat16* __restrict__ M3,
    __hip_bfloat16* __restrict__ M4, float* __restrict__ nrm)
{
    const int tid = threadIdx.x, w = tid >> 6, l = tid & 63;

    if (blockIdx.x >= BATCH) {
        // ---- W conversion: 16384 f32 per block, coalesced x4 ----
        const size_t base = (size_t)(blockIdx.x - BATCH) * 16384;
        #pragma unroll
        for (int it = 0; it < 4; ++it) {
            const size_t idx = base + (size_t)it * 4096 + (size_t)tid * 4;
            const f32x4 v = *reinterpret_cast<const f32x4*>(W + idx);
            ushort4 o;
            o.x = f2bfu(v[0]); o.y = f2bfu(v[1]); o.z = f2bfu(v[2]); o.w = f2bfu(v[3]);
            *reinterpret_cast<ushort4*>(Wbf + idx) = o;
        }
        return;
    }

    __shared__ float rs[256];
    __shared__ float red[16];
    __shared__ float s_alpha;

    const int b = blockIdx.x;
    const float* feat_b = feat + (size_t)b * CDIM * MHW;
    __hip_bfloat16* xcb = xcb_all + (size_t)b * CDIM * MP;
    __hip_bfloat16* m0 = M0 + (size_t)b * CC;
    __hip_bfloat16* m1 = M1 + (size_t)b * CC;
    __hip_bfloat16* m2 = M2 + (size_t)b * CC;
    __hip_bfloat16* m3 = M3 + (size_t)b * CC;
    __hip_bfloat16* m4 = M4 + (size_t)b * CC;

    // phase 0: center 256 rows (16 waves x 16 rows)
    #pragma unroll
    for (int it = 0; it < 16; ++it)
        center_row(feat_b, xcb, rs, it * 16 + w, l);
    __syncthreads();

    // trace = sum(rs) -> s_alpha = 1/tr  (same reduce order as prior rounds)
    if (tid < 256) {
        float v = rs[tid];
        #pragma unroll
        for (int o = 32; o >= 1; o >>= 1) v += __shfl_xor(v, o, 64);
        if (l == 0) red[tid >> 6] = v;
    }
    __syncthreads();
    if (tid == 0) s_alpha = 1.0f / (red[0] + red[1] + red[2] + red[3]);
    __syncthreads();

    // y  = (1/tr) * xc @ xc^T                         -> M0
    if (w < NTRI) mm64<MP,  false>(xcb, xcb, nullptr, m0, s_alpha, 0.0f, 0.0f, w, l);
    __syncthreads();
    // Y1 = -0.5*y@y + 1.5*y                           -> M1
    if (w < NTRI) mm64<256, false>(m0, m0, m0, m1, -0.5f, 1.5f, 0.0f, w, l);
    __syncthreads();
    // T2 = 0.5*y@Y1 - 1.5*Y1 + 3I                     -> M2
    if (w < NTRI) mm64<256, false>(m0, m1, m1, m2, 0.5f, -1.5f, 3.0f, w, l);
    __syncthreads();
    // Y2 = 0.5*Y1@T2 -> M3 ; Z2 = -0.25*T2@y + 0.75*T2 -> M4  (independent)
    if (w < NTRI) {
        mm64<256, false>(m1, m2, nullptr, m3, 0.5f, 0.0f, 0.0f, w, l);
        mm64<256, false>(m2, m0, m2, m4, -0.25f, 0.75f, 0.0f, w, l);
    }
    __syncthreads();
    // T3 = -Z2@Y2 + 3I                                -> M1 (Y1 dead)
    if (w < NTRI) mm64<256, false>(m4, m3, nullptr, m1, -1.0f, 0.0f, 3.0f, w, l);
    __syncthreads();
    // Y3 = 0.5*Y2@T3  (+ Frobenius norm^2)            -> M2 (T2 dead)
    float ns = 0.0f;
    if (w < NTRI) ns = mm64<256, true>(m3, m1, nullptr, m2, 0.5f, 0.0f, 0.0f, w, l);
    #pragma unroll
    for (int o = 32; o >= 1; o >>= 1) ns += __shfl_xor(ns, o, 64);
    if (l == 0) red[w] = ns;
    __syncthreads();
    if (tid == 0) {
        float f = 0.0f;
        #pragma unroll
        for (int q = 0; q < NTRI; ++q) f += red[q];
        nrm[b] = f;
    }
}

// ---------------------------------------------------------------------------
// k_proj2: u[b,e] = sum_k flat[b,k]*Wbf[e,k]; split-K (64 ksplits x 8 etiles),
// block K-chunk 1024 (4 waves x 256), cross-wave LDS reduce -> upart[ks].
// W already bf16 (converted in k_mega) -> half the HBM traffic of f32 W.
// ---------------------------------------------------------------------------
__global__ __launch_bounds__(256) void k_proj2(const __hip_bfloat16* __restrict__ flat,
                                               const __hip_bfloat16* __restrict__ Wbf,
                                               float* __restrict__ upart)
{
    __shared__ float racc[2][64][65];
    const int ks = blockIdx.x, et = blockIdx.y;
    const int tid = threadIdx.x, wv = tid >> 6, l = tid & 63;
    const int lr = l & 15, lg = l >> 4;
    const int kbase = ks * 1024 + wv * 256;

    f32x4 acc[4][4];
    #pragma unroll
    for (int i = 0; i < 4; i++)
        #pragma unroll
        for (int j = 0; j < 4; j++)
            #pragma unroll
            for (int r = 0; r < 4; r++) acc[i][j][r] = 0.0f;

    for (int kk = 0; kk < 256; kk += 32) {
        const int k = kbase + kk + lg * 8;
        short8_t af[4], bfr[4];
        #pragma unroll
        for (int i = 0; i < 4; i++)
            af[i] = *reinterpret_cast<const short8_t*>(flat + (size_t)(i * 16 + lr) * CC + k);
        #pragma unroll
        for (int j = 0; j < 4; j++)
            bfr[j] = *reinterpret_cast<const short8_t*>(Wbf + (size_t)(et * 64 + j * 16 + lr) * CC + k);
        #pragma unroll
        for (int i = 0; i < 4; i++)
            #pragma unroll
            for (int j = 0; j < 4; j++)
                acc[i][j] = __builtin_amdgcn_mfma_f32_16x16x32_bf16(af[i], bfr[j], acc[i][j], 0, 0, 0);
    }

    if (wv >= 2) {
        #pragma unroll
        for (int i = 0; i < 4; i++)
            #pragma unroll
            for (int j = 0; j < 4; j++)
                #pragma unroll
                for (int r = 0; r < 4; r++)
                    racc[wv - 2][i * 16 + lg * 4 + r][j * 16 + lr] = acc[i][j][r];
    }
    __syncthreads();
    if (wv < 2) {
        #pragma unroll
        for (int i = 0; i < 4; i++)
            #pragma unroll
            for (int j = 0; j < 4; j++)
                #pragma unroll
                for (int r = 0; r < 4; r++)
                    racc[wv][i * 16 + lg * 4 + r][j * 16 + lr] += acc[i][j][r];
    }
    __syncthreads();
    float* ub = upart + (size_t)ks * (64 * EDIM);
    #pragma unroll
    for (int q = 0; q < 16; q++) {
        const int idx = q * 256 + tid;
        const int x = idx >> 6, y = idx & 63;
        ub[(size_t)x * EDIM + et * 64 + y] = racc[0][x][y] + racc[1][x][y];
    }
}

// ---------------------------------------------------------------------------
// k_fin: reduce 64 K-partials, 1/||Y3||_F scale, +bias, BN, final L2 norm.
// ---------------------------------------------------------------------------
__global__ __launch_bounds__(256) void k_fin(const float* __restrict__ upart,
                                             const float* __restrict__ nrm,
                                             const float* __restrict__ bias,
                                             const float* __restrict__ gma,
                                             const float* __restrict__ bta,
                                             const float* __restrict__ mu,
                                             const float* __restrict__ var,
                                             float* __restrict__ out)
{
    __shared__ float wsum[4];
    const int bb = blockIdx.x;
    const int tid = threadIdx.x, wv = tid >> 6, l = tid & 63;
    const int e0 = tid, e1 = tid + 256;
    float u0 = 0.0f, u1 = 0.0f;
    for (int p = 0; p < 64; ++p) {
        const float* up = upart + ((size_t)p * 64 + bb) * EDIM;
        u0 += up[e0]; u1 += up[e1];
    }
    const float s = 1.0f / fmaxf(sqrtf(nrm[bb]), 1e-12f);
    const float emb0 = s * u0 + bias[e0];
    const float emb1 = s * u1 + bias[e1];
    const float v0 = (emb0 - mu[e0]) * rsqrtf(var[e0] + 1e-5f) * gma[e0] + bta[e0];
    const float v1 = (emb1 - mu[e1]) * rsqrtf(var[e1] + 1e-5f) * gma[e1] + bta[e1];
    float sq = v0 * v0 + v1 * v1;
    #pragma unroll
    for (int o = 32; o >= 1; o >>= 1) sq += __shfl_xor(sq, o, 64);
    if (l == 0) wsum[wv] = sq;
    __syncthreads();
    const float tot = wsum[0] + wsum[1] + wsum[2] + wsum[3];
    const float rn = 1.0f / fmaxf(sqrtf(tot), 1e-12f);
    out[(size_t)bb * EDIM + e0] = v0 * rn;
    out[(size_t)bb * EDIM + e1] = v1 * rn;
}

// ---------------------------------------------------------------------------
extern "C" void kernel_launch(void* const* d_in, const int* in_sizes, int n_in,
                              void* d_out, int out_size, void* d_ws, size_t ws_size,
                              hipStream_t stream)
{
    const float* feat = (const float*)d_in[0];
    const float* W    = (const float*)d_in[1];
    const float* bias = (const float*)d_in[2];
    const float* gma  = (const float*)d_in[3];
    const float* bta  = (const float*)d_in[4];
    const float* mu   = (const float*)d_in[5];
    const float* var  = (const float*)d_in[6];
    float* out = (float*)d_out;

    char* ws = (char*)d_ws;
    constexpr size_t XCB_BYTES = (size_t)BATCH * CDIM * MP * 2;     //  7,340,032
    constexpr size_t MATB      = (size_t)BATCH * CC * 2;            //  8,388,608
    constexpr size_t WBF_BYTES = (size_t)CC * EDIM * 2;             // 67,108,864
    constexpr size_t OFF_XCB   = 4096;
    constexpr size_t OFF_M     = OFF_XCB + XCB_BYTES;
    constexpr size_t OFF_WBF   = OFF_M + 5 * MATB;
    constexpr size_t OFF_UP    = OFF_WBF + WBF_BYTES;
    constexpr size_t NEEDED    = OFF_UP + (size_t)64 * 64 * EDIM * 4;  // ~125 MB
    if (ws_size < NEEDED) return;

    float* nrm = (float*)(ws + 0);                                   // 64 floats
    __hip_bfloat16* xcb = (__hip_bfloat16*)(ws + OFF_XCB);
    __hip_bfloat16* M0  = (__hip_bfloat16*)(ws + OFF_M + 0 * MATB);
    __hip_bfloat16* M1  = (__hip_bfloat16*)(ws + OFF_M + 1 * MATB);
    __hip_bfloat16* M2  = (__hip_bfloat16*)(ws + OFF_M + 2 * MATB);
    __hip_bfloat16* M3  = (__hip_bfloat16*)(ws + OFF_M + 3 * MATB);
    __hip_bfloat16* M4  = (__hip_bfloat16*)(ws + OFF_M + 4 * MATB);
    __hip_bfloat16* Wbf = (__hip_bfloat16*)(ws + OFF_WBF);
    float* upart = (float*)(ws + OFF_UP);

    k_mega<<<dim3(BATCH + WCONV_BLOCKS), dim3(1024), 0, stream>>>(
        feat, W, xcb, Wbf, M0, M1, M2, M3, M4, nrm);
    k_proj2<<<dim3(64, 8), dim3(256), 0, stream>>>(M2, Wbf, upart);
    k_fin<<<dim3(64), dim3(256), 0, stream>>>(upart, nrm, bias, gma, bta, mu, var, out);
}